// Round 1
// baseline (1176.696 us; speedup 1.0000x reference)
//
#include <hip/hip_runtime.h>
#include <hip/hip_fp16.h>

#define D_MODEL 1024
#define NHEADS  16
#define DEPTH   64
#define BATCH   8
#define SEQ     1024

typedef __attribute__((ext_vector_type(4))) float    floatx4;
typedef __attribute__((ext_vector_type(8))) _Float16 half8;
typedef __attribute__((ext_vector_type(4))) _Float16 half4;

// ---- async global->LDS, 16B per lane (wave-uniform LDS base + lane*16) ----
static __device__ __forceinline__ void async16(const void* g, void* l) {
    auto gp = reinterpret_cast<const __attribute__((address_space(1))) unsigned int*>(
        reinterpret_cast<uintptr_t>(g));
    auto lp = reinterpret_cast<__attribute__((address_space(3))) unsigned int*>(
        reinterpret_cast<uintptr_t>(l));
    __builtin_amdgcn_global_load_lds(gp, lp, 16, 0, 0);
}

// ---- fp32 -> fp16 convert, float4 -> half4 ----
__global__ void cvt_f32_f16(const float* __restrict__ src, _Float16* __restrict__ dst, int n4) {
    int i = blockIdx.x * 256 + threadIdx.x;
    if (i >= n4) return;
    const float4 f = ((const float4*)src)[i];
    half4 o = { (_Float16)f.x, (_Float16)f.y, (_Float16)f.z, (_Float16)f.w };
    ((half4*)dst)[i] = o;
}

// ---- C[M,N] = A[M,K] @ Bw[N,K]^T + bias; A,Bw fp16, fp32 accumulate ----
// 128x128 tile, BK=64, global_load_lds staging, XOR-swizzled LDS chunks.
template <int OUT_HALF>
__global__ __launch_bounds__(256, 2) void gemm_bt(
    const _Float16* __restrict__ A, const _Float16* __restrict__ Bw,
    const float* __restrict__ bias, void* __restrict__ Cout,
    int M, int N, int K)
{
    __shared__ _Float16 sA[128 * 64];   // 16 KB, [row][8 chunks of 8 halfs], chunk XOR-swizzled
    __shared__ _Float16 sB[128 * 64];

    const int tid  = threadIdx.x;
    const int wave = tid >> 6, lane = tid & 63;
    const int quad = lane >> 4, l16 = lane & 15;
    const int bm = blockIdx.x, bn = blockIdx.y;
    const int wy = wave & 1, wx = wave >> 1;

    floatx4 acc[4][4] = {};

    const int srow = wave * 8 + (lane >> 3);          // staging row (+ r*32)
    const int kpp  = lane & 7;                        // physical 16B chunk within row

    for (int k0 = 0; k0 < K; k0 += 64) {
        __syncthreads();
#pragma unroll
        for (int r = 0; r < 4; ++r) {
            const int row = srow + r * 32;
            const int kpl = kpp ^ (row & 7);          // logical chunk to fetch (swizzle)
            const _Float16* gA = A  + (size_t)(bm * 128 + row) * K + k0 + kpl * 8;
            const _Float16* gB = Bw + (size_t)(bn * 128 + row) * K + k0 + kpl * 8;
            async16(gA, sA + (r * 256 + wave * 64) * 8);
            async16(gB, sB + (r * 256 + wave * 64) * 8);
        }
        __syncthreads();
#pragma unroll
        for (int ks = 0; ks < 2; ++ks) {
            half8 af[4], bf[4];
#pragma unroll
            for (int i = 0; i < 4; ++i) {
                const int rowA = wy * 64 + i * 16 + l16;
                af[i] = *(const half8*)(sA + rowA * 64 + (((ks * 4 + quad) ^ (rowA & 7)) * 8));
                const int rowB = wx * 64 + i * 16 + l16;
                bf[i] = *(const half8*)(sB + rowB * 64 + (((ks * 4 + quad) ^ (rowB & 7)) * 8));
            }
#pragma unroll
            for (int i = 0; i < 4; ++i)
#pragma unroll
                for (int j = 0; j < 4; ++j)
                    acc[i][j] = __builtin_amdgcn_mfma_f32_16x16x32_f16(af[i], bf[j], acc[i][j], 0, 0, 0);
        }
    }

#pragma unroll
    for (int i = 0; i < 4; ++i) {
        const int row0 = bm * 128 + wy * 64 + i * 16 + quad * 4;
#pragma unroll
        for (int j = 0; j < 4; ++j) {
            const int col = bn * 128 + wx * 64 + j * 16 + l16;
            const float bv = bias[col];
#pragma unroll
            for (int r = 0; r < 4; ++r) {
                const float vv = acc[i][j][r] + bv;
                if (OUT_HALF) ((_Float16*)Cout)[(size_t)(row0 + r) * N + col] = (_Float16)vv;
                else          ((float*)Cout)   [(size_t)(row0 + r) * N + col] = vv;
            }
        }
    }
}

// ---- V transpose: [B,S,D_MODEL] -> [B*H, DEPTH, S] so PV B-frags are contiguous ----
__global__ __launch_bounds__(256) void transpose_v(const _Float16* __restrict__ vp,
                                                   _Float16* __restrict__ vt) {
    __shared__ _Float16 t[64][72];
    const int tid = threadIdx.x;
    const int s0 = blockIdx.x * 64;
    const int bh = blockIdx.y;
    const int b = bh >> 4, h = bh & 15;
    {
        const int si = tid >> 2, dj = (tid & 3) * 16;
        const _Float16* src = vp + (size_t)(b * SEQ + s0 + si) * D_MODEL + h * 64 + dj;
        *(half8*)&t[si][dj]     = *(const half8*)src;
        *(half8*)&t[si][dj + 8] = *(const half8*)(src + 8);
    }
    __syncthreads();
    {
        const int d = tid >> 2, sj = (tid & 3) * 16;
        _Float16* dst = vt + (size_t)(bh * 64 + d) * SEQ + s0 + sj;
        half8 v0, v1;
#pragma unroll
        for (int j = 0; j < 8; ++j) { v0[j] = t[sj + j][d]; v1[j] = t[sj + 8 + j][d]; }
        *(half8*)dst       = v0;
        *(half8*)(dst + 8) = v1;
    }
}

// ---- fused scores + mask + softmax + attn-write + PV ----
// block: 16 Q-rows x full 1024 keys for one (b,h). 64 KB LDS score strip.
__global__ __launch_bounds__(256) void attn_fused(
    const _Float16* __restrict__ qp, const _Float16* __restrict__ kp,
    const _Float16* __restrict__ vt, const int* __restrict__ mask,
    float* __restrict__ attn, _Float16* __restrict__ ctx)
{
    __shared__ float sc[16 * 1024];   // exactly 64 KB -> 2 blocks/CU
    const int tid  = threadIdx.x;
    const int wave = tid >> 6, lane = tid & 63;
    const int quad = lane >> 4, l16 = lane & 15;
    const int q0 = blockIdx.x * 16;
    const int bh = blockIdx.y;
    const int b = bh >> 4, h = bh & 15;
    const float scale = 1.0f / (sqrtf(64.0f) + 1e-8f);

    // Q fragments (A-operand: m=l16 is Q row, k=quad*8+j)
    half8 qf[2];
#pragma unroll
    for (int ks = 0; ks < 2; ++ks)
        qf[ks] = *(const half8*)(qp + (size_t)(b * SEQ + q0 + l16) * D_MODEL + h * 64 + ks * 32 + quad * 8);

    // Phase 1: scores = scale * Qh Kh^T, masked at store time
    for (int ct = wave; ct < 64; ct += 4) {
        const half8 kf0 = *(const half8*)(kp + (size_t)(b * SEQ + ct * 16 + l16) * D_MODEL + h * 64 + quad * 8);
        const half8 kf1 = *(const half8*)(kp + (size_t)(b * SEQ + ct * 16 + l16) * D_MODEL + h * 64 + 32 + quad * 8);
        floatx4 a = {0.f, 0.f, 0.f, 0.f};
        a = __builtin_amdgcn_mfma_f32_16x16x32_f16(qf[0], kf0, a, 0, 0, 0);
        a = __builtin_amdgcn_mfma_f32_16x16x32_f16(qf[1], kf1, a, 0, 0, 0);
        const int col = ct * 16 + l16;
        float ma = 0.0f;
        if (col > 0 && mask[b * (SEQ - 1) + col - 1] == 0) ma = -__builtin_inff();
#pragma unroll
        for (int r = 0; r < 4; ++r)
            sc[(quad * 4 + r) * 1024 + col] = a[r] * scale + ma;
    }
    __syncthreads();

    // Phases 2+3: softmax per row (16 threads/row), then normalize + write attn + LDS
    const int row = tid >> 4, sub = tid & 15;
    float m = -__builtin_inff();
#pragma unroll 4
    for (int i = 0; i < 16; ++i) {
        const float4 s4 = *(const float4*)&sc[row * 1024 + i * 64 + sub * 4];
        m = fmaxf(fmaxf(fmaxf(s4.x, s4.y), fmaxf(s4.z, s4.w)), m);
    }
#pragma unroll
    for (int o = 1; o < 16; o <<= 1) m = fmaxf(m, __shfl_xor(m, o, 64));
    float ssum = 0.f;
#pragma unroll 4
    for (int i = 0; i < 16; ++i) {
        const float4 s4 = *(const float4*)&sc[row * 1024 + i * 64 + sub * 4];
        ssum += __expf(s4.x - m) + __expf(s4.y - m) + __expf(s4.z - m) + __expf(s4.w - m);
    }
#pragma unroll
    for (int o = 1; o < 16; o <<= 1) ssum += __shfl_xor(ssum, o, 64);
    const float inv = 1.0f / ssum;

    float* arow = attn + ((size_t)bh * SEQ + q0 + row) * SEQ;
#pragma unroll 2
    for (int i = 0; i < 16; ++i) {
        const int c = i * 64 + sub * 4;
        const float4 s4 = *(const float4*)&sc[row * 1024 + c];
        float4 p;
        p.x = __expf(s4.x - m) * inv; p.y = __expf(s4.y - m) * inv;
        p.z = __expf(s4.z - m) * inv; p.w = __expf(s4.w - m) * inv;
        *(float4*)&sc[row * 1024 + c] = p;     // for PV
        *(float4*)&arow[c] = p;                // attn output (in flight during PV)
    }
    __syncthreads();

    // Phase 4: O[16,64] = P[16,1024] @ Vh[1024,64]; wave = depth col-tile
    floatx4 oacc = {0.f, 0.f, 0.f, 0.f};
    for (int k0 = 0; k0 < 1024; k0 += 32) {
        const float4 f0 = *(const float4*)&sc[l16 * 1024 + k0 + quad * 8];
        const float4 f1 = *(const float4*)&sc[l16 * 1024 + k0 + quad * 8 + 4];
        half8 af;
        af[0] = (_Float16)f0.x; af[1] = (_Float16)f0.y; af[2] = (_Float16)f0.z; af[3] = (_Float16)f0.w;
        af[4] = (_Float16)f1.x; af[5] = (_Float16)f1.y; af[6] = (_Float16)f1.z; af[7] = (_Float16)f1.w;
        const half8 vf = *(const half8*)(vt + (size_t)(bh * 64 + wave * 16 + l16) * SEQ + k0 + quad * 8);
        oacc = __builtin_amdgcn_mfma_f32_16x16x32_f16(af, vf, oacc, 0, 0, 0);
    }
#pragma unroll
    for (int r = 0; r < 4; ++r)
        ctx[(size_t)(b * SEQ + q0 + quad * 4 + r) * D_MODEL + h * 64 + wave * 16 + l16] = (_Float16)oacc[r];
}

extern "C" void kernel_launch(void* const* d_in, const int* in_sizes, int n_in,
                              void* d_out, int out_size, void* d_ws, size_t ws_size,
                              hipStream_t stream) {
    (void)in_sizes; (void)n_in; (void)out_size; (void)ws_size;
    const float* q    = (const float*)d_in[0];
    const float* k    = (const float*)d_in[1];
    const float* v    = (const float*)d_in[2];
    const int*   mask = (const int*)d_in[3];
    const float* wq_w = (const float*)d_in[4];
    const float* wq_b = (const float*)d_in[5];
    const float* wk_w = (const float*)d_in[6];
    const float* wk_b = (const float*)d_in[7];
    const float* wv_w = (const float*)d_in[8];
    const float* wv_b = (const float*)d_in[9];
    const float* dw   = (const float*)d_in[10];
    const float* db   = (const float*)d_in[11];

    float* outp  = (float*)d_out;
    float* attnp = outp + (size_t)BATCH * SEQ * D_MODEL;   // tuple: [output | attn]

    const size_t NQKV = (size_t)BATCH * SEQ * D_MODEL;     // 8388608
    const size_t NW   = (size_t)D_MODEL * D_MODEL;         // 1048576
    _Float16* tmpA  = (_Float16*)d_ws;      // input fp16 / later vT   (16.8 MB)
    _Float16* tmpW  = tmpA + NQKV;          // weight fp16             (2 MB)
    _Float16* qproj = tmpW + NW;            // (16.8 MB)
    _Float16* kproj = qproj + NQKV;         // (16.8 MB)
    _Float16* vproj = kproj + NQKV;         // later ctx (16.8 MB)  => ws total ~69.2 MB

    const int M = BATCH * SEQ;              // 8192
    const dim3 gg(M / 128, D_MODEL / 128);  // 64 x 8

    // Q path
    cvt_f32_f16<<<NQKV / 4 / 256, 256, 0, stream>>>(q, tmpA, (int)(NQKV / 4));
    cvt_f32_f16<<<NW / 4 / 256,  256, 0, stream>>>(wq_w, tmpW, (int)(NW / 4));
    gemm_bt<1><<<gg, 256, 0, stream>>>(tmpA, tmpW, wq_b, qproj, M, D_MODEL, D_MODEL);
    // K path
    cvt_f32_f16<<<NQKV / 4 / 256, 256, 0, stream>>>(k, tmpA, (int)(NQKV / 4));
    cvt_f32_f16<<<NW / 4 / 256,  256, 0, stream>>>(wk_w, tmpW, (int)(NW / 4));
    gemm_bt<1><<<gg, 256, 0, stream>>>(tmpA, tmpW, wk_b, kproj, M, D_MODEL, D_MODEL);
    // V path
    cvt_f32_f16<<<NQKV / 4 / 256, 256, 0, stream>>>(v, tmpA, (int)(NQKV / 4));
    cvt_f32_f16<<<NW / 4 / 256,  256, 0, stream>>>(wv_w, tmpW, (int)(NW / 4));
    gemm_bt<1><<<gg, 256, 0, stream>>>(tmpA, tmpW, wv_b, vproj, M, D_MODEL, D_MODEL);
    // vT into tmpA (vb dead)
    transpose_v<<<dim3(SEQ / 64, BATCH * NHEADS), 256, 0, stream>>>(vproj, tmpA);
    // fused attention: reads qproj/kproj/vT, writes attn (d_out) + ctx (vproj region, dead)
    attn_fused<<<dim3(SEQ / 16, BATCH * NHEADS), 256, 0, stream>>>(qproj, kproj, tmpA, mask, attnp, vproj);
    // dense
    cvt_f32_f16<<<NW / 4 / 256, 256, 0, stream>>>(dw, tmpW, (int)(NW / 4));
    gemm_bt<0><<<gg, 256, 0, stream>>>(vproj, tmpW, db, outp, M, D_MODEL, D_MODEL);
}